// Round 4
// baseline (238.739 us; speedup 1.0000x reference)
//
#include <hip/hip_runtime.h>
#include <hip/hip_bf16.h>
#include <stdint.h>

#define EMB    32
#define BATCH  128
#define NU     200000
#define KSEL   50000
#define XCOLS  33
#define SLOTS  64
#define NBLK   256          // sweep grid size (1 block/CU)

// ws layout
#define OFF_SPRE   0
#define OFF_IIDE   16384
#define OFF_GHIST  32768    // 128*256 u32 = 131072; reused as sum_part[256][128] f32 after scan1
#define OFF_BASE16 163840
#define OFF_PREFIX 164352
#define OFF_M2     164864
#define OFF_EQ     165376   // 128 counters, stride 16 u32 (64B)
#define OFF_CAND   173568   // fallback-path cand base
#define OFF_PART   173568   // partials-path: [256][128][256] u32 = 33.55 MB
#define PART_BYTES ((size_t)NBLK * 128 * 256 * 4)

// ---------------- prep ----------------
__global__ void prep_kernel(const float* __restrict__ x,
                            const float* __restrict__ iid_w,
                            const float* __restrict__ rp,
                            const float* __restrict__ uid,
                            float* __restrict__ s_pre,
                            float* __restrict__ iid_emb,
                            uint32_t* __restrict__ base16) {
    const int b = blockIdx.x;
    const int t = threadIdx.x;          // 64 threads
    __shared__ float xr[EMB];
    if (t < EMB) xr[t] = x[b * XCOLS + 1 + t];
    __syncthreads();
    if (t < EMB) {
        float acc = 0.f;
        #pragma unroll
        for (int k = 0; k < EMB; ++k) acc += xr[k] * rp[t * EMB + k];
        s_pre[b * EMB + t] = acc;
    } else {
        const int d = t - EMB;
        const int iid = (int)x[b * XCOLS];
        iid_emb[b * EMB + d] = iid_w[(size_t)iid * EMB + d];
    }
    __syncthreads();
    if (t == 0) {
        float dot = 0.f;
        #pragma unroll
        for (int k = 0; k < EMB; ++k) dot += s_pre[b * EMB + k] * uid[k];
        const uint32_t bits = __float_as_uint(fabsf(dot - 4.0f));
        const uint32_t hi = bits >> 16;
        base16[b] = (hi > 128u) ? (hi - 128u) : 0u;
    }
}

// ---------------- zero scratch ----------------
__global__ void zero_kernel(uint32_t* __restrict__ p, int n) {
    int i = blockIdx.x * blockDim.x + threadIdx.x;
    if (i < n) p[i] = 0u;
}

// ---------------- sweep1: scalar-load u, per-row key histogram ----------------
template <bool PART>
__global__ __launch_bounds__(1024, 4)
void sweep1_kernel(const float* __restrict__ s_pre,
                   const float* __restrict__ uid,
                   const uint32_t* __restrict__ base16,
                   uint32_t* __restrict__ gout,   // PART ? partials : ghist(atomic)
                   int jchunk) {
    extern __shared__ uint32_t hist[];   // [128][257] padded
    const int t  = threadIdx.x;
    const int b  = t & 127;
    const int jl = t >> 7;               // 0..7, wave-uniform
    for (int i = t; i < 128 * 257; i += 1024) hist[i] = 0u;
    float s[EMB];
    #pragma unroll
    for (int d = 0; d < EMB; ++d) s[d] = s_pre[b * EMB + d];
    const uint32_t base = base16[b];
    __syncthreads();

    const int j0 = blockIdx.x * jchunk;
    const int jend = min(j0 + jchunk, NU);
    int j = j0 + jl;
    for (; j + 8 < jend; j += 16) {
        const int ju = __builtin_amdgcn_readfirstlane(j);    // wave-uniform -> SGPR addr
        const float* up0 = uid + (size_t)ju * EMB;
        const float* up1 = up0 + 8 * EMB;
        float d0 = 0.f, d1 = 0.f;
        #pragma unroll
        for (int k = 0; k < EMB; ++k) {
            d0 += s[k] * up0[k];
            d1 += s[k] * up1[k];
        }
        const uint32_t bits0 = __float_as_uint(fabsf(d0 - 4.0f));
        const uint32_t bits1 = __float_as_uint(fabsf(d1 - 4.0f));
        int dg0 = (int)(bits0 >> 16) - (int)base; dg0 = dg0 < 0 ? 0 : (dg0 > 255 ? 255 : dg0);
        int dg1 = (int)(bits1 >> 16) - (int)base; dg1 = dg1 < 0 ? 0 : (dg1 > 255 ? 255 : dg1);
        atomicAdd(&hist[b * 257 + dg0], 1u);
        atomicAdd(&hist[b * 257 + dg1], 1u);
    }
    for (; j < jend; j += 8) {
        const int ju = __builtin_amdgcn_readfirstlane(j);
        const float* up0 = uid + (size_t)ju * EMB;
        float d0 = 0.f;
        #pragma unroll
        for (int k = 0; k < EMB; ++k) d0 += s[k] * up0[k];
        const uint32_t bits0 = __float_as_uint(fabsf(d0 - 4.0f));
        int dg0 = (int)(bits0 >> 16) - (int)base; dg0 = dg0 < 0 ? 0 : (dg0 > 255 ? 255 : dg0);
        atomicAdd(&hist[b * 257 + dg0], 1u);
    }
    __syncthreads();
    if (PART) {
        // plain coalesced store of this block's histogram: part[bid][row][digit]
        uint32_t* part = gout + (size_t)blockIdx.x * 32768;
        for (int i = t * 4; i < 32768; i += 4096) {
            const int row = i >> 8, d = i & 255;
            uint4 v;
            v.x = hist[row * 257 + d + 0];
            v.y = hist[row * 257 + d + 1];
            v.z = hist[row * 257 + d + 2];
            v.w = hist[row * 257 + d + 3];
            *(uint4*)(part + i) = v;
        }
    } else {
        for (int i = t; i < 128 * 256; i += 1024) {
            const uint32_t c = hist[(i >> 8) * 257 + (i & 255)];
            if (c) atomicAdd(&gout[i], c);
        }
    }
}

// ---------------- scan1 (atomic-ghist path) ----------------
__global__ void scan1_kernel(const uint32_t* __restrict__ ghist,
                             const uint32_t* __restrict__ base16,
                             uint32_t* __restrict__ prefix16,
                             uint32_t* __restrict__ m2) {
    const int b = threadIdx.x;           // 128 threads, 1 block
    uint32_t cum = 0, before = 0;
    int c1 = 255;
    for (int d = 0; d < 256; ++d) {
        const uint32_t c = ghist[b * 256 + d];
        if (cum + c >= (uint32_t)KSEL) { c1 = d; before = cum; break; }
        cum += c;
        if (d == 255) before = cum;
    }
    prefix16[b] = base16[b] + (uint32_t)c1;
    m2[b] = (uint32_t)KSEL - before;
}

// ---------------- scan1 (partials path): reduce 256 block-hists, then pick ----------
__global__ __launch_bounds__(256)
void scan1_part_kernel(const uint32_t* __restrict__ part,
                       const uint32_t* __restrict__ base16,
                       uint32_t* __restrict__ prefix16,
                       uint32_t* __restrict__ m2) {
    const int row = blockIdx.x;          // 128 blocks
    const int t = threadIdx.x;           // 256 threads = digits
    __shared__ uint32_t h[256];
    uint32_t a0 = 0, a1 = 0, a2 = 0, a3 = 0;
    const uint32_t* p = part + (size_t)row * 256 + t;
    for (int g = 0; g < NBLK; g += 4) {
        a0 += p[(size_t)(g + 0) * 32768];
        a1 += p[(size_t)(g + 1) * 32768];
        a2 += p[(size_t)(g + 2) * 32768];
        a3 += p[(size_t)(g + 3) * 32768];
    }
    h[t] = a0 + a1 + a2 + a3;
    __syncthreads();
    if (t == 0) {
        uint32_t cum = 0, before = 0; int c1 = 255;
        for (int d = 0; d < 256; ++d) {
            const uint32_t c = h[d];
            if (cum + c >= (uint32_t)KSEL) { c1 = d; before = cum; break; }
            cum += c;
            if (d == 255) before = cum;
        }
        prefix16[row] = base16[row] + (uint32_t)c1;
        m2[row] = (uint32_t)KSEL - before;
    }
}

// ---------------- sweep2: scalar-load u dual-dot; below-sum + candidates ----------
__global__ __launch_bounds__(1024, 4)
void sweep2_kernel(const float* __restrict__ s_pre,
                   const float* __restrict__ iid_emb,
                   const float* __restrict__ uid,
                   const uint32_t* __restrict__ prefix16,
                   uint32_t* __restrict__ eq_cnt,
                   float* __restrict__ sum_part,
                   uint64_t* __restrict__ cand,
                   int cap, int jchunk) {
    extern __shared__ char smem2[];
    uint64_t* lcand = (uint64_t*)smem2;                   // 65536
    uint32_t* lcnt  = (uint32_t*)(smem2 + 65536);         // 512
    uint32_t* lbase = (uint32_t*)(smem2 + 66048);         // 512
    float*    sums  = (float*)(smem2 + 66560);            // 4096
    const int t  = threadIdx.x;
    const int b  = t & 127;
    const int jl = t >> 7;               // wave-uniform
    if (t < 128) lcnt[t] = 0u;
    float s[EMB], e[EMB];
    #pragma unroll
    for (int d = 0; d < EMB; ++d) { s[d] = s_pre[b*EMB+d]; e[d] = iid_emb[b*EMB+d]; }
    const uint32_t pfx = prefix16[b];
    __syncthreads();

    const int j0 = blockIdx.x * jchunk;
    const int jend = min(j0 + jchunk, NU);
    float local = 0.f;
    int j = j0 + jl;
    for (; j + 8 < jend; j += 16) {
        const int ju = __builtin_amdgcn_readfirstlane(j);
        const float* up0 = uid + (size_t)ju * EMB;
        const float* up1 = up0 + 8 * EMB;
        float d0 = 0.f, v0 = 0.f, d1 = 0.f, v1 = 0.f;
        #pragma unroll
        for (int k = 0; k < EMB; ++k) {
            const float u0 = up0[k], u1 = up1[k];
            d0 += s[k] * u0;  v0 += e[k] * u0;
            d1 += s[k] * u1;  v1 += e[k] * u1;
        }
        const uint32_t bits0 = __float_as_uint(fabsf(d0 - 4.0f));
        const uint32_t bits1 = __float_as_uint(fabsf(d1 - 4.0f));
        const uint32_t hi0 = bits0 >> 16, hi1 = bits1 >> 16;
        local += (hi0 < pfx) ? v0 : 0.f;                 // branchless common path
        local += (hi1 < pfx) ? v1 : 0.f;
        if (hi0 == pfx) {
            const uint32_t pos = atomicAdd(&lcnt[b], 1u);
            const uint64_t pk = ((uint64_t)bits0 << 32) | (uint32_t)j;
            if (pos < (uint32_t)SLOTS) lcand[b * SLOTS + pos] = pk;
            else {
                const uint32_t g = atomicAdd(&eq_cnt[b * 16], 1u);
                if (g < (uint32_t)cap) cand[(size_t)b * cap + g] = pk;
            }
        }
        if (hi1 == pfx) {
            const uint32_t pos = atomicAdd(&lcnt[b], 1u);
            const uint64_t pk = ((uint64_t)bits1 << 32) | (uint32_t)(j + 8);
            if (pos < (uint32_t)SLOTS) lcand[b * SLOTS + pos] = pk;
            else {
                const uint32_t g = atomicAdd(&eq_cnt[b * 16], 1u);
                if (g < (uint32_t)cap) cand[(size_t)b * cap + g] = pk;
            }
        }
    }
    for (; j < jend; j += 8) {
        const int ju = __builtin_amdgcn_readfirstlane(j);
        const float* up0 = uid + (size_t)ju * EMB;
        float d0 = 0.f, v0 = 0.f;
        #pragma unroll
        for (int k = 0; k < EMB; ++k) {
            const float u0 = up0[k];
            d0 += s[k] * u0;  v0 += e[k] * u0;
        }
        const uint32_t bits0 = __float_as_uint(fabsf(d0 - 4.0f));
        const uint32_t hi0 = bits0 >> 16;
        local += (hi0 < pfx) ? v0 : 0.f;
        if (hi0 == pfx) {
            const uint32_t pos = atomicAdd(&lcnt[b], 1u);
            const uint64_t pk = ((uint64_t)bits0 << 32) | (uint32_t)j;
            if (pos < (uint32_t)SLOTS) lcand[b * SLOTS + pos] = pk;
            else {
                const uint32_t g = atomicAdd(&eq_cnt[b * 16], 1u);
                if (g < (uint32_t)cap) cand[(size_t)b * cap + g] = pk;
            }
        }
    }
    sums[t] = local;                       // unique slot per thread
    __syncthreads();
    if (t < 128) {
        float acc = 0.f;
        #pragma unroll
        for (int l = 0; l < 8; ++l) acc += sums[l * 128 + t];
        sum_part[blockIdx.x * 128 + t] = acc;
        const uint32_t n = min(lcnt[t], (uint32_t)SLOTS);
        lbase[t] = atomicAdd(&eq_cnt[t * 16], n);
    }
    __syncthreads();
    for (int i = t; i < 128 * SLOTS; i += 1024) {
        const int bb = i >> 6;             // SLOTS == 64
        const int sl = i & 63;
        if (sl < (int)min(lcnt[bb], (uint32_t)SLOTS)) {
            const uint32_t p = lbase[bb] + (uint32_t)sl;
            if (p < (uint32_t)cap) cand[(size_t)bb * cap + p] = lcand[i];
        }
    }
}

// ---------------- finalize ----------------
__global__ __launch_bounds__(256)
void final_kernel(const float* __restrict__ iid_emb,
                  const float* __restrict__ uid,
                  const uint32_t* __restrict__ m2_,
                  const uint32_t* __restrict__ eq_cnt,
                  const float* __restrict__ sum_part,
                  const uint64_t* __restrict__ cand,
                  int cap, float* __restrict__ out) {
    const int b = blockIdx.x;
    const int t = threadIdx.x;           // 256 threads
    __shared__ float red[256];
    __shared__ uint32_t hist[256];
    __shared__ float e[EMB];
    __shared__ uint32_t tie[128];
    __shared__ uint32_t tiecnt, sc2, sm3, sc3, sm4;
    __shared__ float sbelow;
    if (t < EMB) e[t] = iid_emb[b * EMB + t];
    if (t == 0) tiecnt = 0u;
    hist[t] = 0u;
    red[t] = sum_part[t * 128 + b];
    __syncthreads();
    for (int s = 128; s > 0; s >>= 1) { if (t < s) red[t] += red[t + s]; __syncthreads(); }
    if (t == 0) sbelow = red[0];
    __syncthreads();

    const uint32_t ec = eq_cnt[b * 16];
    const int cnt = (int)(ec < (uint32_t)cap ? ec : (uint32_t)cap);
    const uint64_t* cb = cand + (size_t)b * cap;

    for (int i = t; i < cnt; i += 256) {
        const uint32_t low16 = (uint32_t)(cb[i] >> 32) & 0xFFFFu;
        atomicAdd(&hist[low16 >> 8], 1u);
    }
    __syncthreads();
    if (t == 0) {
        const uint32_t m2v = m2_[b];
        uint32_t cum = 0, before = 0; int c2 = 255;
        for (int d = 0; d < 256; ++d) {
            const uint32_t c = hist[d];
            if (cum + c >= m2v) { c2 = d; before = cum; break; }
            cum += c;
        }
        sc2 = (uint32_t)c2; sm3 = m2v - before;
    }
    __syncthreads();
    const uint32_t c2 = sc2;
    hist[t] = 0u;
    __syncthreads();

    for (int i = t; i < cnt; i += 256) {
        const uint32_t low16 = (uint32_t)(cb[i] >> 32) & 0xFFFFu;
        if ((low16 >> 8) == c2) atomicAdd(&hist[low16 & 255u], 1u);
    }
    __syncthreads();
    if (t == 0) {
        const uint32_t m3 = sm3;
        uint32_t cum = 0, before = 0; int c3 = 255;
        for (int d = 0; d < 256; ++d) {
            const uint32_t c = hist[d];
            if (cum + c >= m3) { c3 = d; before = cum; break; }
            cum += c;
        }
        sc3 = (uint32_t)c3; sm4 = m3 - before;
    }
    __syncthreads();
    const uint32_t T16 = (c2 << 8) | sc3;

    float local = 0.f;
    for (int i = t; i < cnt; i += 256) {
        const uint64_t cv = cb[i];
        const uint32_t low16 = (uint32_t)(cv >> 32) & 0xFFFFu;
        if (low16 < T16) {
            const uint32_t j = (uint32_t)cv;
            const float4* u4 = (const float4*)(uid + (size_t)j * EMB);
            float dv = 0.f;
            #pragma unroll
            for (int q = 0; q < 8; ++q) {
                float4 u = u4[q];
                dv += e[4*q+0]*u.x + e[4*q+1]*u.y + e[4*q+2]*u.z + e[4*q+3]*u.w;
            }
            local += dv;
        } else if (low16 == T16) {
            const uint32_t pos = atomicAdd(&tiecnt, 1u);
            if (pos < 128u) tie[pos] = (uint32_t)cv;
        }
    }
    red[t] = local;
    __syncthreads();
    for (int s = 128; s > 0; s >>= 1) { if (t < s) red[t] += red[t + s]; __syncthreads(); }
    if (t == 0) {
        int tc = (int)(tiecnt < 128u ? tiecnt : 128u);
        for (int i = 1; i < tc; ++i) {
            const uint32_t v = tie[i]; int k = i - 1;
            while (k >= 0 && tie[k] > v) { tie[k+1] = tie[k]; --k; }
            tie[k+1] = v;
        }
        const int m4 = (int)sm4;
        float tsum = 0.f;
        for (int i = 0; i < m4 && i < tc; ++i) {
            const uint32_t j = tie[i];
            float dv = 0.f;
            for (int d = 0; d < EMB; ++d) dv += e[d] * uid[(size_t)j * EMB + d];
            tsum += dv;
        }
        out[b] = (sbelow + red[0] + tsum) / (float)KSEL;
    }
}

extern "C" void kernel_launch(void* const* d_in, const int* in_sizes, int n_in,
                              void* d_out, int out_size, void* d_ws, size_t ws_size,
                              hipStream_t stream) {
    const float* x     = (const float*)d_in[0];
    const float* uid   = (const float*)d_in[1];
    const float* iid_w = (const float*)d_in[2];
    const float* rp    = (const float*)d_in[3];
    float* out = (float*)d_out;

    char* ws = (char*)d_ws;
    float*    s_pre    = (float*)(ws + OFF_SPRE);
    float*    iid_emb  = (float*)(ws + OFF_IIDE);
    uint32_t* ghist    = (uint32_t*)(ws + OFF_GHIST);
    float*    sum_part = (float*)(ws + OFF_GHIST);     // overlay after scan1
    uint32_t* base16   = (uint32_t*)(ws + OFF_BASE16);
    uint32_t* prefix16 = (uint32_t*)(ws + OFF_PREFIX);
    uint32_t* m2       = (uint32_t*)(ws + OFF_M2);
    uint32_t* eq_cnt   = (uint32_t*)(ws + OFF_EQ);
    uint32_t* part     = (uint32_t*)(ws + OFF_PART);

    const size_t off_cand2 = OFF_PART + PART_BYTES;
    const bool use_part = ws_size >= off_cand2 + (size_t)128 * 8 * 4096;

    uint64_t* cand;
    int cap;
    if (use_part) {
        cand = (uint64_t*)(ws + off_cand2);
        long long cap_ll = ((long long)ws_size - (long long)off_cand2) / (128LL * 8LL);
        cap = (int)(cap_ll > 16384 ? 16384 : cap_ll);
    } else {
        cand = (uint64_t*)(ws + OFF_CAND);
        long long cap_ll = ((long long)ws_size - OFF_CAND) / (128LL * 8LL);
        cap = (int)(cap_ll > 16384 ? 16384 : (cap_ll < 1 ? 1 : cap_ll));
    }

    {
        const int n = (OFF_CAND - OFF_GHIST) / 4;      // ghist + base16/prefix/m2 + eq_cnt
        zero_kernel<<<(n + 255) / 256, 256, 0, stream>>>((uint32_t*)(ws + OFF_GHIST), n);
    }
    prep_kernel<<<BATCH, 64, 0, stream>>>(x, iid_w, rp, uid, s_pre, iid_emb, base16);

    const int JC = 782;
    if (use_part) {
        sweep1_kernel<true><<<NBLK, 1024, 128 * 257 * 4, stream>>>(s_pre, uid, base16, part, JC);
        scan1_part_kernel<<<BATCH, 256, 0, stream>>>(part, base16, prefix16, m2);
    } else {
        sweep1_kernel<false><<<NBLK, 1024, 128 * 257 * 4, stream>>>(s_pre, uid, base16, ghist, JC);
        scan1_kernel<<<1, 128, 0, stream>>>(ghist, base16, prefix16, m2);
    }

    sweep2_kernel<<<NBLK, 1024, 65536 + 512 + 512 + 4096, stream>>>(s_pre, iid_emb, uid,
                                                                    prefix16, eq_cnt, sum_part,
                                                                    cand, cap, JC);

    final_kernel<<<BATCH, 256, 0, stream>>>(iid_emb, uid, m2, eq_cnt, sum_part,
                                            cand, cap, out);
}